// Round 1
// baseline (116.105 us; speedup 1.0000x reference)
//
#include <hip/hip_runtime.h>
#include <math.h>

#define ALPHA_F 100.0f

constexpr int N_ = 32, C_ = 128, K_ = 64, S_ = 4096;
constexpr int NCHUNK = 8, SCHUNK = S_ / NCHUNK;   // 512
constexpr int TS = 64, NSUB = SCHUNK / TS;        // 8 sub-tiles per chunk

// ---------------- stage 1: soft-assign + partial VLAD accumulation ----------------
__global__ __launch_bounds__(256, 1)
void nv_stage1(const float* __restrict__ x, const float* __restrict__ cent,
               float* __restrict__ vlad_part, float* __restrict__ asum_part) {
  __shared__ float cent_t[C_][K_];     // [c][k]  32 KB
  __shared__ float x_t[C_][TS];        // [c][ts] raw x tile, 32 KB
  __shared__ float x2[TS][C_ + 4];     // [ts][c] normalized (stride 132), 33.8 KB
  __shared__ float a2[TS][K_ + 4];     // [ts][k] logits -> a (stride 68), 17 KB
  __shared__ float invn_s[TS];
  __shared__ float bias_s[K_];
  __shared__ float red_s[4][TS];

  const int t = threadIdx.x;
  const int chunk = blockIdx.x, n = blockIdx.y;

  // load centroids transposed into LDS (one-time; conflicts here are negligible)
  for (int r = 0; r < 32; ++r) {
    int idx = r * 256 + t;                   // idx = k*128 + c
    cent_t[idx & 127][idx >> 7] = cent[idx];
  }
  __syncthreads();
  if (t < K_) {
    float ss = 0.f;
    for (int c = 0; c < C_; ++c) { float v = cent_t[c][t]; ss += v * v; }
    bias_s[t] = -ALPHA_F * sqrtf(ss);
  }
  // (bias_s/invn readers are separated from this write by the in-loop barriers)

  float acc2[8][4];                          // GEMM2 accumulators, persist per chunk
  #pragma unroll
  for (int a = 0; a < 8; ++a)
    #pragma unroll
    for (int b = 0; b < 4; ++b) acc2[a][b] = 0.f;
  float asum_acc = 0.f;                      // valid on t<64 (k = t)

  const int i4 = (t & 15) * 4, j4 = (t >> 4) * 4;  // GEMM1: 4k x 4ts per thread
  const int k8 = (t & 7) * 8,  c4 = (t >> 3) * 4;  // GEMM2: 8k x 4c per thread
  const int p_ts = t & 63, p_q = t >> 6;

  for (int st = 0; st < NSUB; ++st) {
    const int s0 = chunk * SCHUNK + st * TS;

    // 1. global -> LDS: x[n][c][s0..s0+63], coalesced float4
    {
      const float* xb = x + (size_t)n * C_ * S_ + s0;
      const int s4 = (t & 15) * 4, cbase = t >> 4;
      #pragma unroll
      for (int r = 0; r < 8; ++r) {
        int c = r * 16 + cbase;
        float4 v = *(const float4*)(xb + (size_t)c * S_ + s4);
        *(float4*)&x_t[c][s4] = v;
      }
    }
    __syncthreads();

    // 2. per-pixel inverse L2 norm over channels
    {
      float ss = 0.f;
      #pragma unroll 8
      for (int u = 0; u < 32; ++u) { float v = x_t[p_q * 32 + u][p_ts]; ss += v * v; }
      red_s[p_q][p_ts] = ss;
    }
    __syncthreads();
    if (t < TS) {
      float s2 = red_s[0][t] + red_s[1][t] + red_s[2][t] + red_s[3][t];
      invn_s[t] = 1.0f / fmaxf(sqrtf(s2), 1e-12f);
    }
    __syncthreads();

    // 3. GEMM1: logits[k][ts] = 200 * (cent_k . x_ts) * invn[ts] + bias[k]
    {
      float accl[4][4];
      #pragma unroll
      for (int a = 0; a < 4; ++a)
        #pragma unroll
        for (int b = 0; b < 4; ++b) accl[a][b] = 0.f;
      #pragma unroll 8
      for (int c = 0; c < C_; ++c) {
        float4 cv = *(float4*)&cent_t[c][i4];   // 16 distinct addrs/wave -> broadcasty
        float4 xv = *(float4*)&x_t[c][j4];      // 4 distinct addrs/wave  -> broadcast
        float cvv[4] = {cv.x, cv.y, cv.z, cv.w};
        float xvv[4] = {xv.x, xv.y, xv.z, xv.w};
        #pragma unroll
        for (int a = 0; a < 4; ++a)
          #pragma unroll
          for (int b = 0; b < 4; ++b) accl[a][b] += cvv[a] * xvv[b];
      }
      #pragma unroll
      for (int tt = 0; tt < 4; ++tt) {
        float in = invn_s[j4 + tt];
        float4 o;
        o.x = 2.f * ALPHA_F * accl[0][tt] * in + bias_s[i4 + 0];
        o.y = 2.f * ALPHA_F * accl[1][tt] * in + bias_s[i4 + 1];
        o.z = 2.f * ALPHA_F * accl[2][tt] * in + bias_s[i4 + 2];
        o.w = 2.f * ALPHA_F * accl[3][tt] * in + bias_s[i4 + 3];
        *(float4*)&a2[j4 + tt][i4] = o;
      }
    }
    __syncthreads();

    // 4. softmax over k (64) per pixel: 4 lanes/pixel, 16 k each, shuffle-reduce
    {
      const int p = t >> 2, qb = (t & 3) * 16;
      float4 e0 = *(float4*)&a2[p][qb + 0];
      float4 e1 = *(float4*)&a2[p][qb + 4];
      float4 e2 = *(float4*)&a2[p][qb + 8];
      float4 e3 = *(float4*)&a2[p][qb + 12];
      float m = fmaxf(fmaxf(fmaxf(e0.x, e0.y), fmaxf(e0.z, e0.w)),
                      fmaxf(fmaxf(fmaxf(e1.x, e1.y), fmaxf(e1.z, e1.w)),
                            fmaxf(fmaxf(fmaxf(e2.x, e2.y), fmaxf(e2.z, e2.w)),
                                  fmaxf(fmaxf(e3.x, e3.y), fmaxf(e3.z, e3.w)))));
      m = fmaxf(m, __shfl_xor(m, 1));
      m = fmaxf(m, __shfl_xor(m, 2));
      e0.x = expf(e0.x - m); e0.y = expf(e0.y - m); e0.z = expf(e0.z - m); e0.w = expf(e0.w - m);
      e1.x = expf(e1.x - m); e1.y = expf(e1.y - m); e1.z = expf(e1.z - m); e1.w = expf(e1.w - m);
      e2.x = expf(e2.x - m); e2.y = expf(e2.y - m); e2.z = expf(e2.z - m); e2.w = expf(e2.w - m);
      e3.x = expf(e3.x - m); e3.y = expf(e3.y - m); e3.z = expf(e3.z - m); e3.w = expf(e3.w - m);
      float sum = (e0.x + e0.y + e0.z + e0.w) + (e1.x + e1.y + e1.z + e1.w)
                + (e2.x + e2.y + e2.z + e2.w) + (e3.x + e3.y + e3.z + e3.w);
      sum += __shfl_xor(sum, 1);
      sum += __shfl_xor(sum, 2);
      float rd = 1.0f / sum;
      e0.x *= rd; e0.y *= rd; e0.z *= rd; e0.w *= rd;
      e1.x *= rd; e1.y *= rd; e1.z *= rd; e1.w *= rd;
      e2.x *= rd; e2.y *= rd; e2.z *= rd; e2.w *= rd;
      e3.x *= rd; e3.y *= rd; e3.z *= rd; e3.w *= rd;
      *(float4*)&a2[p][qb + 0]  = e0;
      *(float4*)&a2[p][qb + 4]  = e1;
      *(float4*)&a2[p][qb + 8]  = e2;
      *(float4*)&a2[p][qb + 12] = e3;
    }
    __syncthreads();

    // 5. asum[k] accumulation (t<64, k=t), column sums of a2 (<=2-way conflicts)
    if (t < TS) {
      float s = 0.f;
      #pragma unroll 8
      for (int ts = 0; ts < TS; ++ts) s += a2[ts][t];
      asum_acc += s;
    }
    // 6. transpose + normalize: x2[ts][c] = x_t[c][ts] * invn[ts]
    //    swizzled write schedule (c depends on ts) -> <=2-way bank conflicts
    {
      const int ts = t & 63;
      const float in = invn_s[ts];
      const int cb = (t >> 6) * 32;
      #pragma unroll 4
      for (int u = 0; u < 32; ++u) {
        int c = cb + ((u + ts) & 31);
        x2[ts][c] = x_t[c][ts] * in;
      }
    }
    __syncthreads();

    // 7. GEMM2: vlad[k][c] += sum_ts a2[ts][k] * x2[ts][c]
    {
      #pragma unroll 4
      for (int ts = 0; ts < TS; ++ts) {
        float4 a0 = *(float4*)&a2[ts][k8];
        float4 a1 = *(float4*)&a2[ts][k8 + 4];
        float4 xv = *(float4*)&x2[ts][c4];
        float av[8]  = {a0.x, a0.y, a0.z, a0.w, a1.x, a1.y, a1.z, a1.w};
        float xvv[4] = {xv.x, xv.y, xv.z, xv.w};
        #pragma unroll
        for (int a = 0; a < 8; ++a)
          #pragma unroll
          for (int b = 0; b < 4; ++b) acc2[a][b] += av[a] * xvv[b];
      }
    }
    __syncthreads();
  }

  // epilogue: write per-chunk partials (full overwrite -> no init needed)
  {
    const size_t base = (size_t)(n * NCHUNK + chunk) * (K_ * C_);
    #pragma unroll
    for (int kk = 0; kk < 8; ++kk) {
      float4 o = make_float4(acc2[kk][0], acc2[kk][1], acc2[kk][2], acc2[kk][3]);
      *(float4*)&vlad_part[base + (size_t)(k8 + kk) * C_ + c4] = o;
    }
    if (t < K_) asum_part[(n * NCHUNK + chunk) * K_ + t] = asum_acc;
  }
}

// ---------------- stage 2: reduce chunks, subtract, intra-norm, global norm ----------------
__global__ __launch_bounds__(256, 1)
void nv_stage2(const float* __restrict__ vlad_part, const float* __restrict__ asum_part,
               const float* __restrict__ cent, float* __restrict__ out) {
  __shared__ float asum_s[K_];
  __shared__ float redw[4];
  const int t = threadIdx.x, n = blockIdx.x;

  if (t < K_) {
    float s = 0.f;
    for (int ch = 0; ch < NCHUNK; ++ch) s += asum_part[(n * NCHUNK + ch) * K_ + t];
    asum_s[t] = s;
  }
  __syncthreads();

  float4 vp[8];
  float scl[8];
  float tot = 0.f;
  #pragma unroll
  for (int r = 0; r < 8; ++r) {
    const int f = t + 256 * r;          // float4 index in [0,2048)
    const int k = f >> 5, c = (f & 31) * 4;
    float4 acc = make_float4(0.f, 0.f, 0.f, 0.f);
    for (int ch = 0; ch < NCHUNK; ++ch) {
      float4 v = *(const float4*)&vlad_part[((size_t)(n * NCHUNK + ch) * K_ + k) * C_ + c];
      acc.x += v.x; acc.y += v.y; acc.z += v.z; acc.w += v.w;
    }
    const float as = asum_s[k];
    float4 cw = *(const float4*)&cent[k * C_ + c];
    acc.x -= as * cw.x; acc.y -= as * cw.y; acc.z -= as * cw.z; acc.w -= as * cw.w;
    float ssq = acc.x * acc.x + acc.y * acc.y + acc.z * acc.z + acc.w * acc.w;
    // reduce over the 32 lanes that share this k (contiguous lanes, same wave)
    #pragma unroll
    for (int w = 1; w <= 16; w <<= 1) ssq += __shfl_xor(ssq, w);
    float sc = 1.0f / fmaxf(sqrtf(ssq), 1e-12f);
    vp[r] = acc; scl[r] = sc;
    tot += ssq * sc * sc * (1.0f / 32.0f);  // each of 32 lanes contributes same value
  }
  // block-reduce total sum-of-squares of intra-normalized vector
  #pragma unroll
  for (int w = 1; w <= 32; w <<= 1) tot += __shfl_xor(tot, w);
  if ((t & 63) == 0) redw[t >> 6] = tot;
  __syncthreads();
  const float total = redw[0] + redw[1] + redw[2] + redw[3];
  const float rfin = 1.0f / fmaxf(sqrtf(total), 1e-12f);

  #pragma unroll
  for (int r = 0; r < 8; ++r) {
    const int f = t + 256 * r;
    const int k = f >> 5, c = (f & 31) * 4;
    const float s = scl[r] * rfin;
    float4 o = make_float4(vp[r].x * s, vp[r].y * s, vp[r].z * s, vp[r].w * s);
    *(float4*)&out[(size_t)n * (K_ * C_) + k * C_ + c] = o;
  }
}

extern "C" void kernel_launch(void* const* d_in, const int* in_sizes, int n_in,
                              void* d_out, int out_size, void* d_ws, size_t ws_size,
                              hipStream_t stream) {
  const float* x    = (const float*)d_in[0];   // [32,128,64,64] fp32
  const float* cent = (const float*)d_in[1];   // [64,128] fp32
  float* out = (float*)d_out;                  // [32, 8192] fp32

  float* vlad_part = (float*)d_ws;                                   // N*NCHUNK*K*C floats
  float* asum_part = vlad_part + (size_t)N_ * NCHUNK * K_ * C_;      // N*NCHUNK*K floats

  dim3 g1(NCHUNK, N_);
  nv_stage1<<<g1, 256, 0, stream>>>(x, cent, vlad_part, asum_part);
  nv_stage2<<<N_, 256, 0, stream>>>(vlad_part, asum_part, cent, out);
}

// Round 2
// 104.291 us; speedup vs baseline: 1.1133x; 1.1133x over previous
//
#include <hip/hip_runtime.h>
#include <math.h>

#define ALPHA_F 100.0f

constexpr int N_ = 32, C_ = 128, K_ = 64, S_ = 4096;
constexpr int NCHUNK = 8, SCHUNK = S_ / NCHUNK;   // 512
constexpr int TS = 64, NSUB = SCHUNK / TS;        // 8 sub-tiles per chunk
constexpr int NT = 512;                           // 8 waves/block = 2 waves/SIMD

// ---------------- stage 1: soft-assign + partial VLAD accumulation ----------------
__global__ __launch_bounds__(NT, 1)
void nv_stage1(const float* __restrict__ x, const float* __restrict__ cent,
               float* __restrict__ vlad_part, float* __restrict__ asum_part) {
  __shared__ float cent_t[C_][K_];     // [c][k]  32 KB
  __shared__ float x_t[C_][TS];        // [c][ts] raw x tile, 32 KB
  __shared__ float x2[TS][C_ + 4];     // [ts][c] normalized (stride 132), 33.8 KB
  __shared__ float a2[TS][K_ + 4];     // [ts][k] logits -> a (stride 68), 17 KB
  __shared__ float invn_s[TS];
  __shared__ float bias_s[K_];
  __shared__ float red_s[8][TS];       // 2 KB

  const int t = threadIdx.x;
  const int chunk = blockIdx.x, n = blockIdx.y;

  // load centroids transposed into LDS (one-time)
  #pragma unroll
  for (int r = 0; r < 16; ++r) {
    int idx = r * NT + t;                    // idx = k*128 + c
    cent_t[idx & 127][idx >> 7] = cent[idx];
  }
  __syncthreads();
  if (t < K_) {
    float ss = 0.f;
    for (int c = 0; c < C_; ++c) { float v = cent_t[c][t]; ss += v * v; }
    bias_s[t] = -ALPHA_F * sqrtf(ss);
  }
  // (bias_s readers are separated from this write by the in-loop barriers)

  float acc2[4][4];                          // GEMM2 accumulators (4k x 4c), persist per chunk
  #pragma unroll
  for (int a = 0; a < 4; ++a)
    #pragma unroll
    for (int b = 0; b < 4; ++b) acc2[a][b] = 0.f;
  float asum_acc = 0.f;                      // valid on t<128 (k=t&63, half=t>>6)

  const int g1k = (t & 15) * 4, g1s = (t >> 4) * 2;  // GEMM1: 4k x 2ts
  const int g2k = (t & 15) * 4, g2c = (t >> 4) * 4;  // GEMM2: 4k x 4c
  const int p_ts = t & 63, p_q = t >> 6;             // norm: 8 groups x 16 channels

  for (int st = 0; st < NSUB; ++st) {
    const int s0 = chunk * SCHUNK + st * TS;

    // 1. global -> LDS: x[n][c][s0..s0+63], coalesced float4
    {
      const float* xb = x + (size_t)n * C_ * S_ + s0;
      const int s4 = (t & 15) * 4, cbase = t >> 4;   // cbase in [0,32)
      #pragma unroll
      for (int r = 0; r < 4; ++r) {
        int c = r * 32 + cbase;
        float4 v = *(const float4*)(xb + (size_t)c * S_ + s4);
        *(float4*)&x_t[c][s4] = v;
      }
    }
    __syncthreads();

    // 2. per-pixel inverse L2 norm over channels (8 partial groups)
    {
      float ss = 0.f;
      #pragma unroll
      for (int u = 0; u < 16; ++u) { float v = x_t[p_q * 16 + u][p_ts]; ss += v * v; }
      red_s[p_q][p_ts] = ss;
    }
    __syncthreads();
    if (t < TS) {
      float s2 = 0.f;
      #pragma unroll
      for (int q = 0; q < 8; ++q) s2 += red_s[q][t];
      invn_s[t] = 1.0f / fmaxf(sqrtf(s2), 1e-12f);
    }
    __syncthreads();

    // 3. GEMM1: logits[k][ts] = 200 * (cent_k . x_ts) * invn[ts] + bias[k]
    {
      float accl[4][2];
      #pragma unroll
      for (int a = 0; a < 4; ++a) { accl[a][0] = 0.f; accl[a][1] = 0.f; }
      #pragma unroll 8
      for (int c = 0; c < C_; ++c) {
        float4 cv = *(float4*)&cent_t[c][g1k];   // 16 distinct b128/wave
        float2 xv = *(float2*)&x_t[c][g1s];      // 4 distinct b64/wave (broadcast)
        accl[0][0] += cv.x * xv.x; accl[0][1] += cv.x * xv.y;
        accl[1][0] += cv.y * xv.x; accl[1][1] += cv.y * xv.y;
        accl[2][0] += cv.z * xv.x; accl[2][1] += cv.z * xv.y;
        accl[3][0] += cv.w * xv.x; accl[3][1] += cv.w * xv.y;
      }
      #pragma unroll
      for (int tt = 0; tt < 2; ++tt) {
        float in = invn_s[g1s + tt];
        float4 o;
        o.x = 2.f * ALPHA_F * accl[0][tt] * in + bias_s[g1k + 0];
        o.y = 2.f * ALPHA_F * accl[1][tt] * in + bias_s[g1k + 1];
        o.z = 2.f * ALPHA_F * accl[2][tt] * in + bias_s[g1k + 2];
        o.w = 2.f * ALPHA_F * accl[3][tt] * in + bias_s[g1k + 3];
        *(float4*)&a2[g1s + tt][g1k] = o;
      }
    }
    __syncthreads();

    // 4. softmax over k (64) per pixel: 8 lanes/pixel, 8 k each, shuffle-reduce
    {
      const int p = t >> 3, qb = (t & 7) * 8;
      float4 e0 = *(float4*)&a2[p][qb + 0];
      float4 e1 = *(float4*)&a2[p][qb + 4];
      float m = fmaxf(fmaxf(fmaxf(e0.x, e0.y), fmaxf(e0.z, e0.w)),
                      fmaxf(fmaxf(e1.x, e1.y), fmaxf(e1.z, e1.w)));
      m = fmaxf(m, __shfl_xor(m, 1));
      m = fmaxf(m, __shfl_xor(m, 2));
      m = fmaxf(m, __shfl_xor(m, 4));
      e0.x = expf(e0.x - m); e0.y = expf(e0.y - m); e0.z = expf(e0.z - m); e0.w = expf(e0.w - m);
      e1.x = expf(e1.x - m); e1.y = expf(e1.y - m); e1.z = expf(e1.z - m); e1.w = expf(e1.w - m);
      float sum = (e0.x + e0.y + e0.z + e0.w) + (e1.x + e1.y + e1.z + e1.w);
      sum += __shfl_xor(sum, 1);
      sum += __shfl_xor(sum, 2);
      sum += __shfl_xor(sum, 4);
      float rd = 1.0f / sum;
      e0.x *= rd; e0.y *= rd; e0.z *= rd; e0.w *= rd;
      e1.x *= rd; e1.y *= rd; e1.z *= rd; e1.w *= rd;
      *(float4*)&a2[p][qb + 0] = e0;
      *(float4*)&a2[p][qb + 4] = e1;
    }
    __syncthreads();

    // 5. asum[k] partial accumulation: 128 threads, each sums half a column
    if (t < 128) {
      const int k = t & 63, h0 = (t >> 6) * 32;
      float s = 0.f;
      #pragma unroll 8
      for (int u = 0; u < 32; ++u) s += a2[h0 + u][k];
      asum_acc += s;
    }
    // 6. transpose + normalize: x2[ts][c] = x_t[c][ts] * invn[ts]
    //    write schedule c = cb + ((u + ts/4)&15) -> collision-free banks
    {
      const int ts = t & 63;
      const float in = invn_s[ts];
      const int cb = (t >> 6) * 16;
      #pragma unroll 4
      for (int u = 0; u < 16; ++u) {
        int c = cb + ((u + (ts >> 2)) & 15);
        x2[ts][c] = x_t[c][ts] * in;
      }
    }
    __syncthreads();

    // 7. GEMM2: vlad[k][c] += sum_ts a2[ts][k] * x2[ts][c]
    {
      #pragma unroll 4
      for (int ts = 0; ts < TS; ++ts) {
        float4 av = *(float4*)&a2[ts][g2k];     // 16 distinct b128/wave
        float4 xv = *(float4*)&x2[ts][g2c];     // 4 distinct b128/wave (broadcast)
        acc2[0][0] += av.x * xv.x; acc2[0][1] += av.x * xv.y; acc2[0][2] += av.x * xv.z; acc2[0][3] += av.x * xv.w;
        acc2[1][0] += av.y * xv.x; acc2[1][1] += av.y * xv.y; acc2[1][2] += av.y * xv.z; acc2[1][3] += av.y * xv.w;
        acc2[2][0] += av.z * xv.x; acc2[2][1] += av.z * xv.y; acc2[2][2] += av.z * xv.z; acc2[2][3] += av.z * xv.w;
        acc2[3][0] += av.w * xv.x; acc2[3][1] += av.w * xv.y; acc2[3][2] += av.w * xv.z; acc2[3][3] += av.w * xv.w;
      }
    }
    __syncthreads();
  }

  // epilogue: write per-chunk partials (full overwrite -> no init needed)
  {
    const size_t base = (size_t)(n * NCHUNK + chunk) * (K_ * C_);
    #pragma unroll
    for (int kk = 0; kk < 4; ++kk) {
      float4 o = make_float4(acc2[kk][0], acc2[kk][1], acc2[kk][2], acc2[kk][3]);
      *(float4*)&vlad_part[base + (size_t)(g2k + kk) * C_ + g2c] = o;
    }
    if (t < 128) red_s[t >> 6][t & 63] = asum_acc;
    __syncthreads();
    if (t < K_) asum_part[(n * NCHUNK + chunk) * K_ + t] = red_s[0][t] + red_s[1][t];
  }
}

// ---------------- stage 2: reduce chunks, subtract, intra-norm, global norm ----------------
__global__ __launch_bounds__(256, 1)
void nv_stage2(const float* __restrict__ vlad_part, const float* __restrict__ asum_part,
               const float* __restrict__ cent, float* __restrict__ out) {
  __shared__ float asum_s[K_];
  __shared__ float redw[4];
  const int t = threadIdx.x, n = blockIdx.x;

  if (t < K_) {
    float s = 0.f;
    for (int ch = 0; ch < NCHUNK; ++ch) s += asum_part[(n * NCHUNK + ch) * K_ + t];
    asum_s[t] = s;
  }
  __syncthreads();

  float4 vp[8];
  float scl[8];
  float tot = 0.f;
  #pragma unroll
  for (int r = 0; r < 8; ++r) {
    const int f = t + 256 * r;          // float4 index in [0,2048)
    const int k = f >> 5, c = (f & 31) * 4;
    float4 acc = make_float4(0.f, 0.f, 0.f, 0.f);
    for (int ch = 0; ch < NCHUNK; ++ch) {
      float4 v = *(const float4*)&vlad_part[((size_t)(n * NCHUNK + ch) * K_ + k) * C_ + c];
      acc.x += v.x; acc.y += v.y; acc.z += v.z; acc.w += v.w;
    }
    const float as = asum_s[k];
    float4 cw = *(const float4*)&cent[k * C_ + c];
    acc.x -= as * cw.x; acc.y -= as * cw.y; acc.z -= as * cw.z; acc.w -= as * cw.w;
    float ssq = acc.x * acc.x + acc.y * acc.y + acc.z * acc.z + acc.w * acc.w;
    // reduce over the 32 lanes that share this k (contiguous lanes, same wave)
    #pragma unroll
    for (int w = 1; w <= 16; w <<= 1) ssq += __shfl_xor(ssq, w);
    float sc = 1.0f / fmaxf(sqrtf(ssq), 1e-12f);
    vp[r] = acc; scl[r] = sc;
    tot += ssq * sc * sc * (1.0f / 32.0f);  // each of 32 lanes contributes same value
  }
  // block-reduce total sum-of-squares of intra-normalized vector
  #pragma unroll
  for (int w = 1; w <= 32; w <<= 1) tot += __shfl_xor(tot, w);
  if ((t & 63) == 0) redw[t >> 6] = tot;
  __syncthreads();
  const float total = redw[0] + redw[1] + redw[2] + redw[3];
  const float rfin = 1.0f / fmaxf(sqrtf(total), 1e-12f);

  #pragma unroll
  for (int r = 0; r < 8; ++r) {
    const int f = t + 256 * r;
    const int k = f >> 5, c = (f & 31) * 4;
    const float s = scl[r] * rfin;
    float4 o = make_float4(vp[r].x * s, vp[r].y * s, vp[r].z * s, vp[r].w * s);
    *(float4*)&out[(size_t)n * (K_ * C_) + k * C_ + c] = o;
  }
}

extern "C" void kernel_launch(void* const* d_in, const int* in_sizes, int n_in,
                              void* d_out, int out_size, void* d_ws, size_t ws_size,
                              hipStream_t stream) {
  const float* x    = (const float*)d_in[0];   // [32,128,64,64] fp32
  const float* cent = (const float*)d_in[1];   // [64,128] fp32
  float* out = (float*)d_out;                  // [32, 8192] fp32

  float* vlad_part = (float*)d_ws;                                   // N*NCHUNK*K*C floats
  float* asum_part = vlad_part + (size_t)N_ * NCHUNK * K_ * C_;      // N*NCHUNK*K floats

  dim3 g1(NCHUNK, N_);
  nv_stage1<<<g1, NT, 0, stream>>>(x, cent, vlad_part, asum_part);
  nv_stage2<<<N_, 256, 0, stream>>>(vlad_part, asum_part, cent, out);
}

// Round 3
// 46.471 us; speedup vs baseline: 2.4984x; 2.2442x over previous
//
#include <hip/hip_runtime.h>
#include <math.h>

#define ALPHA_F 100.0f

constexpr int N_ = 32, C_ = 128, K_ = 64, S_ = 4096;
constexpr int NCHUNK = 8, SCHUNK = S_ / NCHUNK;  // 512
constexpr int ST = 128, NSUB = SCHUNK / ST;      // 4 subtiles of 128 pixels
constexpr int NT = 512;                          // 8 waves

typedef __attribute__((ext_vector_type(8))) short bf16x8;
typedef __attribute__((ext_vector_type(4))) float f32x4;

__device__ __forceinline__ short f2b(float f) {
  union { float f; unsigned u; } v; v.f = f;
  unsigned r = v.u + 0x7FFFu + ((v.u >> 16) & 1u);   // round-to-nearest-even
  return (short)(r >> 16);
}
__device__ __forceinline__ float b2f(short b) {
  union { unsigned u; float f; } v; v.u = ((unsigned)(unsigned short)b) << 16;
  return v.f;
}
__device__ __forceinline__ unsigned pk2(short a, short b) {
  return ((unsigned)(unsigned short)a) | (((unsigned)(unsigned short)b) << 16);
}
// lgkm-only barrier: keeps global prefetch (vmcnt) in flight across phases
#define BARRIER() do { asm volatile("s_waitcnt lgkmcnt(0)" ::: "memory"); \
                       __builtin_amdgcn_s_barrier(); } while (0)

// ---------------- stage 1: MFMA soft-assign + partial VLAD ----------------
__global__ __launch_bounds__(NT, 2)
void nv_stage1(const float* __restrict__ x, const float* __restrict__ cent,
               float* __restrict__ vlad_part, float* __restrict__ asum_part) {
  __shared__ short x2h[ST][136];   // x-hat hi, [s][c] (chunk-swizzled)  34.8 KB
  __shared__ short x2l[ST][136];   // x-hat lo                           34.8 KB
  __shared__ short xbh[C_][136];   // x-hat hi, [c][s]                   34.8 KB
  __shared__ short cl_s[K_][136];  // centroid lo, [k][c]                17.4 KB
  __shared__ short a_th[K_][136];  // a bf16, [k][s]; aliased as scratch 17.4 KB
  __shared__ float invn_s[ST];
  __shared__ float bias_s[K_];

  float* scratch = (float*)&a_th[0][0];  // 4352 floats: red @0, asum_w @2048

  const int t = threadIdx.x;
  const int l = t & 63, w = t >> 6;
  const int l16 = l & 15, g = l >> 4;       // 16-lane col / 4-row group
  const int cq = t >> 4, so = t & 15;       // staging map: c-quad, s-octet
  const int chunk = blockIdx.x, n = blockIdx.y;
  const int sb = w * 16, cb = w * 16;       // wave's s-mtile (GEMM1) / c-mtile (GEMM2)

  const float* xg = x + (size_t)n * C_ * S_ + (size_t)chunk * SCHUNK;

  // ---- prologue: first staging loads (c = cq*4+i, s = so*8..+8)
  float xr[4][8];
  #pragma unroll
  for (int i = 0; i < 4; ++i) {
    const float* p = xg + (size_t)(cq * 4 + i) * S_ + so * 8;
    float4 u = *(const float4*)p, v = *(const float4*)(p + 4);
    xr[i][0] = u.x; xr[i][1] = u.y; xr[i][2] = u.z; xr[i][3] = u.w;
    xr[i][4] = v.x; xr[i][5] = v.y; xr[i][6] = v.z; xr[i][7] = v.w;
  }

  // bias partial sums (k = t&63, c-range w*16..+16)
  {
    const float* cr = cent + (t & 63) * C_ + w * 16;
    float ss = 0.f;
    #pragma unroll
    for (int h = 0; h < 4; ++h) {
      float4 v = *(const float4*)(cr + h * 4);
      ss += v.x * v.x + v.y * v.y + v.z * v.z + v.w * v.w;
    }
    scratch[w * 64 + (t & 63)] = ss;
  }
  // centroid-lo -> LDS (k = t>>3, c = (t&7)*16 .. +16)
  {
    const int k = t >> 3, c0 = (t & 7) * 16;
    const float* cr = cent + k * C_ + c0;
    unsigned* dst = (unsigned*)&cl_s[k][c0];
    #pragma unroll
    for (int h = 0; h < 4; ++h) {
      float4 v = *(const float4*)(cr + h * 4);
      short a0 = f2b(v.x - b2f(f2b(v.x))), a1 = f2b(v.y - b2f(f2b(v.y)));
      short a2 = f2b(v.z - b2f(f2b(v.z))), a3 = f2b(v.w - b2f(f2b(v.w)));
      dst[h * 2 + 0] = pk2(a0, a1);
      dst[h * 2 + 1] = pk2(a2, a3);
    }
  }
  // centroid-hi B-fragments in registers: chf[nt][ks], col k = nt*16+l16, kdim c
  bf16x8 chf[4][4];
  #pragma unroll
  for (int nt2 = 0; nt2 < 4; ++nt2)
    #pragma unroll
    for (int ks = 0; ks < 4; ++ks) {
      const float* cr = cent + (nt2 * 16 + l16) * C_ + ks * 32 + g * 8;
      float4 a = *(const float4*)cr, b = *(const float4*)(cr + 4);
      bf16x8 f;
      f[0] = f2b(a.x); f[1] = f2b(a.y); f[2] = f2b(a.z); f[3] = f2b(a.w);
      f[4] = f2b(b.x); f[5] = f2b(b.y); f[6] = f2b(b.z); f[7] = f2b(b.w);
      chf[nt2][ks] = f;
    }
  __syncthreads();
  if (t < 64) {
    float ss = 0.f;
    #pragma unroll
    for (int q = 0; q < 8; ++q) ss += scratch[q * 64 + t];
    bias_s[t] = -ALPHA_F * sqrtf(ss);
  }
  __syncthreads();
  float bias_r[4];
  #pragma unroll
  for (int nt2 = 0; nt2 < 4; ++nt2) bias_r[nt2] = bias_s[nt2 * 16 + l16];

  f32x4 acc2[4];
  #pragma unroll
  for (int nt2 = 0; nt2 < 4; ++nt2) { f32x4 z = {0.f, 0.f, 0.f, 0.f}; acc2[nt2] = z; }
  float asum_acc[4] = {0.f, 0.f, 0.f, 0.f};

  for (int st = 0; st < NSUB; ++st) {
    // ---- A: per-pixel inv-norm from staged regs
    BARRIER();
    float ss[8];
    #pragma unroll
    for (int j = 0; j < 8; ++j)
      ss[j] = xr[0][j] * xr[0][j] + xr[1][j] * xr[1][j]
            + xr[2][j] * xr[2][j] + xr[3][j] * xr[3][j];
    #pragma unroll
    for (int j = 0; j < 8; ++j) {
      ss[j] += __shfl_xor(ss[j], 16);
      ss[j] += __shfl_xor(ss[j], 32);
    }
    if (g == 0) {
      float4 w0 = make_float4(ss[0], ss[1], ss[2], ss[3]);
      float4 w1 = make_float4(ss[4], ss[5], ss[6], ss[7]);
      *(float4*)&scratch[w * 132 + so * 8]     = w0;
      *(float4*)&scratch[w * 132 + so * 8 + 4] = w1;
    }
    BARRIER();
    if (t < ST) {
      float s2 = 0.f;
      #pragma unroll
      for (int q = 0; q < 8; ++q) s2 += scratch[q * 132 + t];
      invn_s[t] = 1.0f / fmaxf(sqrtf(s2), 1e-12f);
    }
    BARRIER();
    // ---- C: scale, convert, write bf16 operand tiles
    {
      float4 i0 = *(float4*)&invn_s[so * 8], i1 = *(float4*)&invn_s[so * 8 + 4];
      float inj[8] = {i0.x, i0.y, i0.z, i0.w, i1.x, i1.y, i1.z, i1.w};
      #pragma unroll
      for (int i = 0; i < 4; ++i)
        #pragma unroll
        for (int j = 0; j < 8; ++j) xr[i][j] *= inj[j];
      #pragma unroll
      for (int i = 0; i < 4; ++i) {            // xbh rows: [c][s], b128
        bf16x8 r;
        #pragma unroll
        for (int j = 0; j < 8; ++j) r[j] = f2b(xr[i][j]);
        *(bf16x8*)&xbh[cq * 4 + i][so * 8] = r;
      }
      #pragma unroll
      for (int j = 0; j < 8; ++j) {            // x2 h/l: [s][c], chunk-swizzled
        int s = so * 8 + j;
        int pc = (((cq >> 1) ^ (so & 7)) * 8) + (cq & 1) * 4;
        short h0 = f2b(xr[0][j]), h1 = f2b(xr[1][j]);
        short h2 = f2b(xr[2][j]), h3 = f2b(xr[3][j]);
        uint2 ph; ph.x = pk2(h0, h1); ph.y = pk2(h2, h3);
        *(uint2*)&x2h[s][pc] = ph;
        short e0 = f2b(xr[0][j] - b2f(h0)), e1 = f2b(xr[1][j] - b2f(h1));
        short e2 = f2b(xr[2][j] - b2f(h2)), e3 = f2b(xr[3][j] - b2f(h3));
        uint2 pl; pl.x = pk2(e0, e1); pl.y = pk2(e2, e3);
        *(uint2*)&x2l[s][pc] = pl;
      }
    }
    // prefetch next subtile into xr (stays in flight across lgkm barriers)
    if (st + 1 < NSUB) {
      const float* pg = xg + (st + 1) * ST + so * 8;
      #pragma unroll
      for (int i = 0; i < 4; ++i) {
        const float* p = pg + (size_t)(cq * 4 + i) * S_;
        float4 u = *(const float4*)p, v = *(const float4*)(p + 4);
        xr[i][0] = u.x; xr[i][1] = u.y; xr[i][2] = u.z; xr[i][3] = u.w;
        xr[i][4] = v.x; xr[i][5] = v.y; xr[i][6] = v.z; xr[i][7] = v.w;
      }
    }
    BARRIER();
    // ---- D: GEMM1 (logits_T[s][k] = x2 . cent^T) + softmax + a_t write
    bf16x8 ah[4], al[4];
    {
      int s = sb + l16;
      int nu = (s >> 3) & 7;
      #pragma unroll
      for (int ks = 0; ks < 4; ++ks) {
        int pc = ((ks * 4 + g) ^ nu) * 8;
        ah[ks] = *(const bf16x8*)&x2h[s][pc];
        al[ks] = *(const bf16x8*)&x2l[s][pc];
      }
    }
    f32x4 acc1[4];
    #pragma unroll
    for (int nt2 = 0; nt2 < 4; ++nt2) { f32x4 z = {0.f, 0.f, 0.f, 0.f}; acc1[nt2] = z; }
    #pragma unroll
    for (int nt2 = 0; nt2 < 4; ++nt2)
      #pragma unroll
      for (int ks = 0; ks < 4; ++ks) {
        acc1[nt2] = __builtin_amdgcn_mfma_f32_16x16x32_bf16(ah[ks], chf[nt2][ks], acc1[nt2], 0, 0, 0);
        acc1[nt2] = __builtin_amdgcn_mfma_f32_16x16x32_bf16(al[ks], chf[nt2][ks], acc1[nt2], 0, 0, 0);
        bf16x8 clf = *(const bf16x8*)&cl_s[nt2 * 16 + l16][ks * 32 + g * 8];
        acc1[nt2] = __builtin_amdgcn_mfma_f32_16x16x32_bf16(ah[ks], clf, acc1[nt2], 0, 0, 0);
      }
    {
      float v[4][4];
      #pragma unroll
      for (int nt2 = 0; nt2 < 4; ++nt2)
        #pragma unroll
        for (int i = 0; i < 4; ++i)
          v[nt2][i] = 2.f * ALPHA_F * acc1[nt2][i] + bias_r[nt2];
      float mx[4], sm[4];
      #pragma unroll
      for (int i = 0; i < 4; ++i) {
        mx[i] = fmaxf(fmaxf(v[0][i], v[1][i]), fmaxf(v[2][i], v[3][i]));
        mx[i] = fmaxf(mx[i], __shfl_xor(mx[i], 1));
        mx[i] = fmaxf(mx[i], __shfl_xor(mx[i], 2));
        mx[i] = fmaxf(mx[i], __shfl_xor(mx[i], 4));
        mx[i] = fmaxf(mx[i], __shfl_xor(mx[i], 8));
        sm[i] = 0.f;
      }
      #pragma unroll
      for (int nt2 = 0; nt2 < 4; ++nt2)
        #pragma unroll
        for (int i = 0; i < 4; ++i) {
          float e = __expf(v[nt2][i] - mx[i]);
          v[nt2][i] = e; sm[i] += e;
        }
      #pragma unroll
      for (int i = 0; i < 4; ++i) {
        sm[i] += __shfl_xor(sm[i], 1);
        sm[i] += __shfl_xor(sm[i], 2);
        sm[i] += __shfl_xor(sm[i], 4);
        sm[i] += __shfl_xor(sm[i], 8);
        sm[i] = 1.0f / sm[i];
      }
      #pragma unroll
      for (int nt2 = 0; nt2 < 4; ++nt2) {
        float a0 = v[nt2][0] * sm[0], a1 = v[nt2][1] * sm[1];
        float a2 = v[nt2][2] * sm[2], a3 = v[nt2][3] * sm[3];
        asum_acc[nt2] += a0 + a1 + a2 + a3;
        uint2 pa; pa.x = pk2(f2b(a0), f2b(a1)); pa.y = pk2(f2b(a2), f2b(a3));
        *(uint2*)&a_th[nt2 * 16 + l16][sb + g * 4] = pa;   // [k][s], 4 consecutive s
      }
    }
    BARRIER();
    // ---- E: GEMM2 (vlad_T[c][k] += xbh . a_t), accumulate in regs
    bf16x8 xq[4];
    #pragma unroll
    for (int ks = 0; ks < 4; ++ks)
      xq[ks] = *(const bf16x8*)&xbh[cb + l16][ks * 32 + g * 8];
    #pragma unroll
    for (int nt2 = 0; nt2 < 4; ++nt2)
      #pragma unroll
      for (int ks = 0; ks < 4; ++ks) {
        bf16x8 bq = *(const bf16x8*)&a_th[nt2 * 16 + l16][ks * 32 + g * 8];
        acc2[nt2] = __builtin_amdgcn_mfma_f32_16x16x32_bf16(xq[ks], bq, acc2[nt2], 0, 0, 0);
      }
  }

  // ---- epilogue: per-chunk partials
  BARRIER();
  #pragma unroll
  for (int nt2 = 0; nt2 < 4; ++nt2) {
    float vv = asum_acc[nt2];
    vv += __shfl_xor(vv, 16);
    vv += __shfl_xor(vv, 32);
    if (g == 0) scratch[2048 + w * 64 + nt2 * 16 + l16] = vv;
  }
  const size_t base = (size_t)(n * NCHUNK + chunk) * (K_ * C_);
  #pragma unroll
  for (int nt2 = 0; nt2 < 4; ++nt2) {
    int k = nt2 * 16 + l16;
    float4 o = make_float4(acc2[nt2][0], acc2[nt2][1], acc2[nt2][2], acc2[nt2][3]);
    *(float4*)&vlad_part[base + (size_t)k * C_ + cb + g * 4] = o;
  }
  BARRIER();
  if (t < 64) {
    float sum2 = 0.f;
    #pragma unroll
    for (int q = 0; q < 8; ++q) sum2 += scratch[2048 + q * 64 + t];
    asum_part[(n * NCHUNK + chunk) * K_ + t] = sum2;
  }
}

// ---------------- stage 2: reduce chunks, subtract, intra-norm, global norm ----------------
__global__ __launch_bounds__(256, 1)
void nv_stage2(const float* __restrict__ vlad_part, const float* __restrict__ asum_part,
               const float* __restrict__ cent, float* __restrict__ out) {
  __shared__ float asum_s[K_];
  __shared__ float redw[4];
  const int t = threadIdx.x, n = blockIdx.x;

  if (t < K_) {
    float s = 0.f;
    for (int ch = 0; ch < NCHUNK; ++ch) s += asum_part[(n * NCHUNK + ch) * K_ + t];
    asum_s[t] = s;
  }
  __syncthreads();

  float4 vp[8];
  float scl[8];
  float tot = 0.f;
  #pragma unroll
  for (int r = 0; r < 8; ++r) {
    const int f = t + 256 * r;
    const int k = f >> 5, c = (f & 31) * 4;
    float4 acc = make_float4(0.f, 0.f, 0.f, 0.f);
    for (int ch = 0; ch < NCHUNK; ++ch) {
      float4 v = *(const float4*)&vlad_part[((size_t)(n * NCHUNK + ch) * K_ + k) * C_ + c];
      acc.x += v.x; acc.y += v.y; acc.z += v.z; acc.w += v.w;
    }
    const float as = asum_s[k];
    float4 cw = *(const float4*)&cent[k * C_ + c];
    acc.x -= as * cw.x; acc.y -= as * cw.y; acc.z -= as * cw.z; acc.w -= as * cw.w;
    float ssq = acc.x * acc.x + acc.y * acc.y + acc.z * acc.z + acc.w * acc.w;
    #pragma unroll
    for (int wd = 1; wd <= 16; wd <<= 1) ssq += __shfl_xor(ssq, wd);
    float sc = 1.0f / fmaxf(sqrtf(ssq), 1e-12f);
    vp[r] = acc; scl[r] = sc;
    tot += ssq * sc * sc * (1.0f / 32.0f);
  }
  #pragma unroll
  for (int wd = 1; wd <= 32; wd <<= 1) tot += __shfl_xor(tot, wd);
  if ((t & 63) == 0) redw[t >> 6] = tot;
  __syncthreads();
  const float total = redw[0] + redw[1] + redw[2] + redw[3];
  const float rfin = 1.0f / fmaxf(sqrtf(total), 1e-12f);

  #pragma unroll
  for (int r = 0; r < 8; ++r) {
    const int f = t + 256 * r;
    const int k = f >> 5, c = (f & 31) * 4;
    const float s = scl[r] * rfin;
    float4 o = make_float4(vp[r].x * s, vp[r].y * s, vp[r].z * s, vp[r].w * s);
    *(float4*)&out[(size_t)n * (K_ * C_) + k * C_ + c] = o;
  }
}

extern "C" void kernel_launch(void* const* d_in, const int* in_sizes, int n_in,
                              void* d_out, int out_size, void* d_ws, size_t ws_size,
                              hipStream_t stream) {
  const float* x    = (const float*)d_in[0];   // [32,128,64,64] fp32
  const float* cent = (const float*)d_in[1];   // [64,128] fp32
  float* out = (float*)d_out;                  // [32, 8192] fp32

  float* vlad_part = (float*)d_ws;                                // N*NCHUNK*K*C floats
  float* asum_part = vlad_part + (size_t)N_ * NCHUNK * K_ * C_;   // N*NCHUNK*K floats

  dim3 g1(NCHUNK, N_);
  nv_stage1<<<g1, NT, 0, stream>>>(x, cent, vlad_part, asum_part);
  nv_stage2<<<N_, 256, 0, stream>>>(vlad_part, asum_part, cent, out);
}